// Round 1
// baseline (372.604 us; speedup 1.0000x reference)
//
#include <hip/hip_runtime.h>

typedef __attribute__((ext_vector_type(8))) short bf16x8;
typedef __attribute__((ext_vector_type(4))) float f32x4;

#define D_IN 256
#define D_OUT 256
#define KDIM 512
#define TM 32

static __device__ __forceinline__ unsigned short f2bf(float f) {
    union { float f; unsigned int u; } x; x.f = f;
    unsigned int r = (x.u + 0x7FFFu + ((x.u >> 16) & 1u)) >> 16;
    return (unsigned short)r;
}

// ---------------- binning ----------------
__global__ void count_kernel(const int* __restrict__ dst, int* __restrict__ deg, int E) {
    int e = blockIdx.x * 256 + threadIdx.x;
    if (e < E) atomicAdd(&deg[dst[e]], 1);
}

__global__ void scan_kernel(const int* __restrict__ deg, int* __restrict__ offsets, int n) {
    __shared__ int ssum[1024];
    int t = threadIdx.x;
    int C = (n + 1023) >> 10;
    int lo = t * C;
    int hi = lo + C; if (hi > n) hi = n;
    int s = 0;
    for (int i = lo; i < hi; ++i) s += deg[i];
    int v = s;
    ssum[t] = v;
    __syncthreads();
    for (int off = 1; off < 1024; off <<= 1) {
        int u = (t >= off) ? ssum[t - off] : 0;
        __syncthreads();
        v += u;
        ssum[t] = v;
        __syncthreads();
    }
    int run = v - s;   // exclusive prefix
    for (int i = lo; i < hi; ++i) { offsets[i] = run; run += deg[i]; }
    if (t == 1023) offsets[n] = run;
}

__global__ void scatter_kernel(const int* __restrict__ dst, const int* __restrict__ offsets,
                               int* __restrict__ cursor, int* __restrict__ edge_order, int E) {
    int e = blockIdx.x * 256 + threadIdx.x;
    if (e < E) {
        int d = dst[e];
        int p = atomicAdd(&cursor[d], 1);
        edge_order[offsets[d] + p] = e;
    }
}

// ---------------- pre-pack W into bf16 B-fragments ----------------
// layout: wf[((nt*16 + kk)*64 + lane)*8 + j] = bf16(W[kk*32 + (lane>>4)*8 + j][nt*16 + (lane&15)])
__global__ void wfrag_kernel(const float* __restrict__ W, unsigned short* __restrict__ wf) {
    int t = blockIdx.x * 256 + threadIdx.x;
    if (t >= 16 * 16 * 64) return;
    int l  = t & 63;
    int kk = (t >> 6) & 15;
    int nt = t >> 10;
    int c  = nt * 16 + (l & 15);
    int kb = kk * 32 + (l >> 4) * 8;
    union { unsigned short u[8]; uint4 v; } pk;
#pragma unroll
    for (int j = 0; j < 8; ++j) pk.u[j] = f2bf(W[(size_t)(kb + j) * D_OUT + c]);
    *reinterpret_cast<uint4*>(&wf[(size_t)t * 8]) = pk.v;
}

// ---------------- fused aggregate + GEMM ----------------
__global__ __launch_bounds__(256) void fused_kernel(
    const float* __restrict__ src_feats,
    const float* __restrict__ edge_feats,
    const int* __restrict__ src_idx,
    const int* __restrict__ edge_order,
    const int* __restrict__ offsets,
    const unsigned short* __restrict__ wfrag,
    const float* __restrict__ bias,
    float* __restrict__ out,
    int n_dst)
{
    __shared__ __align__(16) unsigned short aggs[TM][KDIM + 8]; // bf16 bits, padded stride
    __shared__ float norm_s[TM];

    const int tid = threadIdx.x;
    const int wv = tid >> 6;
    const int ln = tid & 63;
    const int base = blockIdx.x * TM;

    // ---- aggregation: wave wv owns rows wv, wv+4, ... ----
    const int half = ln >> 5;            // 0: src half, 1: edge half
    const int sub  = (ln & 31) * 8;      // 8 floats per lane
    for (int r = wv; r < TM; r += 4) {
        int gd = base + r;
        int s = 0, eend = 0;
        if (gd < n_dst) { s = offsets[gd]; eend = offsets[gd + 1]; }
        float4 a0 = make_float4(0.f, 0.f, 0.f, 0.f);
        float4 a1 = make_float4(0.f, 0.f, 0.f, 0.f);
        for (int p = s; p < eend; ++p) {
            int e = edge_order[p];
            int rid = half ? e : src_idx[e];
            const float* rowp = (half ? edge_feats : src_feats) + (size_t)rid * D_IN + sub;
            float4 v0 = *(const float4*)(rowp);
            float4 v1 = *(const float4*)(rowp + 4);
            a0.x += v0.x; a0.y += v0.y; a0.z += v0.z; a0.w += v0.w;
            a1.x += v1.x; a1.y += v1.y; a1.z += v1.z; a1.w += v1.w;
        }
        if (ln == 0) norm_s[r] = (eend > s) ? rsqrtf((float)(eend - s)) : 0.0f;
        union { unsigned short u[8]; uint4 v; } pk;
        pk.u[0] = f2bf(a0.x); pk.u[1] = f2bf(a0.y); pk.u[2] = f2bf(a0.z); pk.u[3] = f2bf(a0.w);
        pk.u[4] = f2bf(a1.x); pk.u[5] = f2bf(a1.y); pk.u[6] = f2bf(a1.z); pk.u[7] = f2bf(a1.w);
        int col = half * 256 + sub;
        *reinterpret_cast<uint4*>(&aggs[r][col]) = pk.v;
    }
    __syncthreads();

    // ---- GEMM: out[32 x 256] = aggs[32 x 512] @ W[512 x 256] (bf16 MFMA) ----
    const int lrow = ln & 15;
    const int lgrp = ln >> 4;
    f32x4 acc[2][4];
#pragma unroll
    for (int m = 0; m < 2; ++m)
#pragma unroll
        for (int n = 0; n < 4; ++n) acc[m][n] = (f32x4)(0.0f);

#pragma unroll
    for (int kk = 0; kk < 16; ++kk) {
        int kb = kk * 32 + lgrp * 8;
        bf16x8 A0 = *reinterpret_cast<const bf16x8*>(&aggs[lrow][kb]);
        bf16x8 A1 = *reinterpret_cast<const bf16x8*>(&aggs[16 + lrow][kb]);
#pragma unroll
        for (int n = 0; n < 4; ++n) {
            int nt = wv * 4 + n;
            bf16x8 B = *reinterpret_cast<const bf16x8*>(&wfrag[(((size_t)nt * 16 + kk) * 64 + ln) * 8]);
            acc[0][n] = __builtin_amdgcn_mfma_f32_16x16x32_bf16(A0, B, acc[0][n], 0, 0, 0);
            acc[1][n] = __builtin_amdgcn_mfma_f32_16x16x32_bf16(A1, B, acc[1][n], 0, 0, 0);
        }
    }

    // ---- epilogue: norm + bias, fp32 store ----
#pragma unroll
    for (int n = 0; n < 4; ++n) {
        int col = wv * 64 + n * 16 + lrow;
        float bv = bias[col];
#pragma unroll
        for (int mt = 0; mt < 2; ++mt) {
#pragma unroll
            for (int j = 0; j < 4; ++j) {
                int r = mt * 16 + lgrp * 4 + j;
                int gd = base + r;
                if (gd < n_dst)
                    out[(size_t)gd * D_OUT + col] = acc[mt][n][j] * norm_s[r] + bv;
            }
        }
    }
}

extern "C" void kernel_launch(void* const* d_in, const int* in_sizes, int n_in,
                              void* d_out, int out_size, void* d_ws, size_t ws_size,
                              hipStream_t stream) {
    const float* src_feats  = (const float*)d_in[0];
    const float* edge_feats = (const float*)d_in[1];
    const int*   src_idx    = (const int*)d_in[2];
    const int*   dst_idx    = (const int*)d_in[3];
    const float* weights    = (const float*)d_in[4];
    const float* h_bias     = (const float*)d_in[5];

    const int E     = in_sizes[2];
    const int n_dst = out_size / D_OUT;
    float* out = (float*)d_out;

    char* ws = (char*)d_ws;
    unsigned short* wfrag = (unsigned short*)ws;                 // 16*16*64*8*2 = 262144 B
    int* deg        = (int*)(ws + 262144);
    int* offsets    = deg + n_dst;           // n_dst + 1
    int* cursor     = offsets + n_dst + 1;
    int* edge_order = cursor + n_dst;        // E ints

    hipMemsetAsync(deg, 0, sizeof(int) * (size_t)n_dst, stream);
    hipMemsetAsync(cursor, 0, sizeof(int) * (size_t)n_dst, stream);

    count_kernel<<<(E + 255) / 256, 256, 0, stream>>>(dst_idx, deg, E);
    scan_kernel<<<1, 1024, 0, stream>>>(deg, offsets, n_dst);
    scatter_kernel<<<(E + 255) / 256, 256, 0, stream>>>(dst_idx, offsets, cursor, edge_order, E);
    wfrag_kernel<<<64, 256, 0, stream>>>(weights, wfrag);

    fused_kernel<<<(n_dst + TM - 1) / TM, 256, 0, stream>>>(
        src_feats, edge_feats, src_idx, edge_order, offsets, wfrag, h_bias, out, n_dst);
}

// Round 2
// 286.966 us; speedup vs baseline: 1.2984x; 1.2984x over previous
//
#include <hip/hip_runtime.h>

typedef __attribute__((ext_vector_type(8))) short bf16x8;
typedef __attribute__((ext_vector_type(4))) float f32x4;

#define D_IN 256
#define D_OUT 256
#define KDIM 512
#define TM 32

static __device__ __forceinline__ unsigned short f2bf(float f) {
    union { float f; unsigned int u; } x; x.f = f;
    unsigned int r = (x.u + 0x7FFFu + ((x.u >> 16) & 1u)) >> 16;
    return (unsigned short)r;
}

// ---------------- binning ----------------
__global__ void count_kernel(const int* __restrict__ dst, int* __restrict__ deg, int E) {
    int e = blockIdx.x * 256 + threadIdx.x;
    if (e < E) atomicAdd(&deg[dst[e]], 1);
}

__global__ void scan_kernel(const int* __restrict__ deg, int* __restrict__ offsets, int n) {
    __shared__ int ssum[1024];
    int t = threadIdx.x;
    int C = (n + 1023) >> 10;
    int lo = t * C;
    int hi = lo + C; if (hi > n) hi = n;
    int s = 0;
    for (int i = lo; i < hi; ++i) s += deg[i];
    int v = s;
    ssum[t] = v;
    __syncthreads();
    for (int off = 1; off < 1024; off <<= 1) {
        int u = (t >= off) ? ssum[t - off] : 0;
        __syncthreads();
        v += u;
        ssum[t] = v;
        __syncthreads();
    }
    int run = v - s;   // exclusive prefix
    for (int i = lo; i < hi; ++i) { offsets[i] = run; run += deg[i]; }
    if (t == 1023) offsets[n] = run;
}

// writes int2{edge_id, src_id} so the gather loop has one indirection level
__global__ void scatter_kernel(const int* __restrict__ dst, const int* __restrict__ src_idx,
                               const int* __restrict__ offsets,
                               int* __restrict__ cursor, int2* __restrict__ rec, int E) {
    int e = blockIdx.x * 256 + threadIdx.x;
    if (e < E) {
        int d = dst[e];
        int p = atomicAdd(&cursor[d], 1);
        rec[offsets[d] + p] = make_int2(e, src_idx[e]);
    }
}

// ---------------- pre-pack W into bf16 B-fragments ----------------
// layout: wf[((nt*16 + kk)*64 + lane)*8 + j] = bf16(W[kk*32 + (lane>>4)*8 + j][nt*16 + (lane&15)])
__global__ void wfrag_kernel(const float* __restrict__ W, unsigned short* __restrict__ wf) {
    int t = blockIdx.x * 256 + threadIdx.x;
    if (t >= 16 * 16 * 64) return;
    int l  = t & 63;
    int kk = (t >> 6) & 15;
    int nt = t >> 10;
    int c  = nt * 16 + (l & 15);
    int kb = kk * 32 + (l >> 4) * 8;
    union { unsigned short u[8]; uint4 v; } pk;
#pragma unroll
    for (int j = 0; j < 8; ++j) pk.u[j] = f2bf(W[(size_t)(kb + j) * D_OUT + c]);
    *reinterpret_cast<uint4*>(&wf[(size_t)t * 8]) = pk.v;
}

#define ACC8(P) do {                                                    \
    float4 _v0 = *(const float4*)(P);                                   \
    float4 _v1 = *(const float4*)((P) + 4);                             \
    a0.x += _v0.x; a0.y += _v0.y; a0.z += _v0.z; a0.w += _v0.w;         \
    a1.x += _v1.x; a1.y += _v1.y; a1.z += _v1.z; a1.w += _v1.w;         \
} while (0)

// ---------------- fused aggregate + GEMM ----------------
__global__ __launch_bounds__(256) void fused_kernel(
    const float* __restrict__ src_feats,
    const float* __restrict__ edge_feats,
    const int2* __restrict__ rec,
    const int* __restrict__ offsets,
    const unsigned short* __restrict__ wfrag,
    const float* __restrict__ bias,
    float* __restrict__ out,
    int n_dst)
{
    __shared__ __align__(16) unsigned short aggs[TM][KDIM + 8]; // bf16 bits, padded stride
    __shared__ float norm_s[TM];

    const int tid = threadIdx.x;
    const int wv = tid >> 6;
    const int ln = tid & 63;
    const int base = blockIdx.x * TM;

    // preload block's 33 row offsets, lane-parallel
    int off_l = 0;
    {
        int i = base + ln;
        if (i > n_dst) i = n_dst;
        if (ln <= TM) off_l = offsets[i];
    }

    // ---- aggregation: wave wv owns rows wv, wv+4, ... ----
    const int half = ln >> 5;            // 0: src half, 1: edge half
    const int sub  = (ln & 31) * 8;      // 8 floats per lane
    const float* fbase = (half ? edge_feats : src_feats) + sub;

    for (int r = wv; r < TM; r += 4) {
        int s    = __shfl(off_l, r);
        int eend = __shfl(off_l, r + 1);
        float4 a0 = make_float4(0.f, 0.f, 0.f, 0.f);
        float4 a1 = make_float4(0.f, 0.f, 0.f, 0.f);

        for (int c = s; c < eend; c += 64) {
            int cnt = eend - c; if (cnt > 64) cnt = 64;
            int2 id = make_int2(0, 0);
            if (ln < cnt) id = rec[c + ln];
            int p = 0;
            for (; p + 4 <= cnt; p += 4) {
                int e0 = __shfl(id.x, p),     s0 = __shfl(id.y, p);
                int e1 = __shfl(id.x, p + 1), s1 = __shfl(id.y, p + 1);
                int e2 = __shfl(id.x, p + 2), s2 = __shfl(id.y, p + 2);
                int e3 = __shfl(id.x, p + 3), s3 = __shfl(id.y, p + 3);
                const float* p0 = fbase + (size_t)(half ? e0 : s0) * D_IN;
                const float* p1 = fbase + (size_t)(half ? e1 : s1) * D_IN;
                const float* p2 = fbase + (size_t)(half ? e2 : s2) * D_IN;
                const float* p3 = fbase + (size_t)(half ? e3 : s3) * D_IN;
                ACC8(p0); ACC8(p1); ACC8(p2); ACC8(p3);
            }
            for (; p < cnt; ++p) {
                int ee = __shfl(id.x, p), ss = __shfl(id.y, p);
                const float* pp = fbase + (size_t)(half ? ee : ss) * D_IN;
                ACC8(pp);
            }
        }
        if (ln == 0) norm_s[r] = (eend > s) ? rsqrtf((float)(eend - s)) : 0.0f;
        union { unsigned short u[8]; uint4 v; } pk;
        pk.u[0] = f2bf(a0.x); pk.u[1] = f2bf(a0.y); pk.u[2] = f2bf(a0.z); pk.u[3] = f2bf(a0.w);
        pk.u[4] = f2bf(a1.x); pk.u[5] = f2bf(a1.y); pk.u[6] = f2bf(a1.z); pk.u[7] = f2bf(a1.w);
        int col = half * 256 + sub;
        *reinterpret_cast<uint4*>(&aggs[r][col]) = pk.v;
    }
    __syncthreads();

    // ---- GEMM: out[32 x 256] = aggs[32 x 512] @ W[512 x 256] (bf16 MFMA) ----
    const int lrow = ln & 15;
    const int lgrp = ln >> 4;
    f32x4 acc[2][4];
#pragma unroll
    for (int m = 0; m < 2; ++m)
#pragma unroll
        for (int n = 0; n < 4; ++n) acc[m][n] = (f32x4)(0.0f);

#pragma unroll
    for (int kk = 0; kk < 16; ++kk) {
        int kb = kk * 32 + lgrp * 8;
        bf16x8 A0 = *reinterpret_cast<const bf16x8*>(&aggs[lrow][kb]);
        bf16x8 A1 = *reinterpret_cast<const bf16x8*>(&aggs[16 + lrow][kb]);
#pragma unroll
        for (int n = 0; n < 4; ++n) {
            int nt = wv * 4 + n;
            bf16x8 B = *reinterpret_cast<const bf16x8*>(&wfrag[(((size_t)nt * 16 + kk) * 64 + ln) * 8]);
            acc[0][n] = __builtin_amdgcn_mfma_f32_16x16x32_bf16(A0, B, acc[0][n], 0, 0, 0);
            acc[1][n] = __builtin_amdgcn_mfma_f32_16x16x32_bf16(A1, B, acc[1][n], 0, 0, 0);
        }
    }

    // ---- epilogue: norm + bias, fp32 store ----
#pragma unroll
    for (int n = 0; n < 4; ++n) {
        int col = wv * 64 + n * 16 + lrow;
        float bv = bias[col];
#pragma unroll
        for (int mt = 0; mt < 2; ++mt) {
#pragma unroll
            for (int j = 0; j < 4; ++j) {
                int r = mt * 16 + lgrp * 4 + j;
                int gd = base + r;
                if (gd < n_dst)
                    out[(size_t)gd * D_OUT + col] = acc[mt][n][j] * norm_s[r] + bv;
            }
        }
    }
}

extern "C" void kernel_launch(void* const* d_in, const int* in_sizes, int n_in,
                              void* d_out, int out_size, void* d_ws, size_t ws_size,
                              hipStream_t stream) {
    const float* src_feats  = (const float*)d_in[0];
    const float* edge_feats = (const float*)d_in[1];
    const int*   src_idx    = (const int*)d_in[2];
    const int*   dst_idx    = (const int*)d_in[3];
    const float* weights    = (const float*)d_in[4];
    const float* h_bias     = (const float*)d_in[5];

    const int E     = in_sizes[2];
    const int n_dst = out_size / D_OUT;
    float* out = (float*)d_out;

    char* ws = (char*)d_ws;
    unsigned short* wfrag = (unsigned short*)ws;            // 262144 B
    int2* rec       = (int2*)(ws + 262144);                 // E * 8 B
    int*  deg       = (int*)(ws + 262144 + (size_t)E * 8);
    int*  offsets   = deg + n_dst;                          // n_dst + 1
    int*  cursor    = offsets + n_dst + 1;

    hipMemsetAsync(deg, 0, sizeof(int) * (size_t)n_dst, stream);
    hipMemsetAsync(cursor, 0, sizeof(int) * (size_t)n_dst, stream);

    count_kernel<<<(E + 255) / 256, 256, 0, stream>>>(dst_idx, deg, E);
    scan_kernel<<<1, 1024, 0, stream>>>(deg, offsets, n_dst);
    scatter_kernel<<<(E + 255) / 256, 256, 0, stream>>>(dst_idx, src_idx, deg /*unused*/ == nullptr ? nullptr : offsets, cursor, rec, E);
    wfrag_kernel<<<64, 256, 0, stream>>>(weights, wfrag);

    fused_kernel<<<(n_dst + TM - 1) / TM, 256, 0, stream>>>(
        src_feats, edge_feats, rec, offsets, wfrag, h_bias, out, n_dst);
}